// Round 13
// baseline (278.366 us; speedup 1.0000x reference)
//
#include <hip/hip_runtime.h>
#include <hip/hip_bf16.h>
#include <math.h>

#define NN 50000
#define NE 800000
#define NREL 4
#define NHEAD 8
#define NSEG (NREL * NN)            // 200000 (rel,dst) segments
#define BCAP 22                     // bucket capacity (Poisson(4) tail ~5e-11)

typedef __hip_bfloat16 bf16;
typedef short short8 __attribute__((ext_vector_type(8)));
typedef float floatx4 __attribute__((ext_vector_type(4)));

#define LOG2E 1.4426950408889634f

__device__ __forceinline__ float b2f(bf16 v) { return __bfloat162float(v); }
__device__ __forceinline__ float us2f(unsigned short u) {
    return __uint_as_float(((unsigned)u) << 16);
}
__device__ __forceinline__ unsigned short f2us(float v) {
    bf16 b = __float2bfloat16(v);
    return *(unsigned short*)&b;
}

// Exact-enough GELU: erf via Abramowitz-Stegun 7.1.26 (|err| <= 1.5e-7).
__device__ __forceinline__ float gelu_f(float v) {
    float z = v * 0.70710678118654752f;
    float az = fabsf(z);
    float t = __builtin_amdgcn_rcpf(__builtin_fmaf(0.3275911f, az, 1.f));
    float p = t * (0.254829592f +
              t * (-0.284496736f +
              t * (1.421413741f +
              t * (-1.453152027f +
              t * 1.061405429f))));
    float ex = __builtin_amdgcn_exp2f(az * az * -LOG2E);
    float er = copysignf(1.f - p * ex, z);
    return 0.5f * v * (1.f + er);
}

// ---------------------------------------------------------------------------
// Diagnostic: fill out with 1000.0 when ws_size is insufficient
// ---------------------------------------------------------------------------
__global__ void fill_kernel(float* __restrict__ out, int n) {
    int t = blockIdx.x * blockDim.x + threadIdx.x;
    if (t < n) out[t] = 1000.0f;
}

// ---------------------------------------------------------------------------
// Fused prep + edge scatter. 800000 threads (== NE, == NN*16).
// Wt[768][128]: rows 0..511 W_rel, 512..639 W_self, 640..671 es-vectors,
//               672..703 ed-vectors, 704..711 ts-vectors (log2e*W_self@asl_h),
//               712..719 td-vectors (log2e*W_self@adl_h), 720..767 zero.
// Wct_ext[144][128]: rows 0..127 W_cross^T; rows 128..135 ls-vectors
//               (log2e * W_cross @ att_src_lang per head); 136..143 zero.
// ---------------------------------------------------------------------------
__global__ __launch_bounds__(256) void prep_scatter(
    const float* __restrict__ W_rel,
    const float* __restrict__ W_self,
    const float* __restrict__ W_cross,
    const float* __restrict__ a_src,
    const float* __restrict__ a_dst,
    const float* __restrict__ a_src_lang,
    const float* __restrict__ a_dst_lang,
    const float* __restrict__ node_inp,
    const int* __restrict__ ei,
    const int* __restrict__ et,
    bf16* __restrict__ Wt, bf16* __restrict__ Wct,
    bf16* __restrict__ Ab,
    int* __restrict__ counts,
    unsigned short* __restrict__ bkt) {
    int t = blockIdx.x * blockDim.x + threadIdx.x;

    // --- edge scatter: issue the atomic as early as possible ---
    int src = 0, pos = BCAP;
    unsigned seg = 0;
    if (t < NE) {
        src = ei[t];
        int dst = ei[NE + t];
        seg = (unsigned)(et[t] * NN + dst);
        pos = atomicAdd(&counts[seg], 1);
    }

    // --- weight packs (small head of the grid) ---
    if (t < 768 * 128) {
        int row = t >> 7, k = t & 127;
        float v;
        if (row < 512) {
            int r = row >> 7, c = row & 127;
            v = W_rel[(r * 128 + k) * 128 + c];
        } else if (row < 640) {
            v = W_self[k * 128 + (row - 512)];
        } else if (row < 704) {
            int q = row - 640;
            bool is_src = q < 32;
            int qq = is_src ? q : q - 32;
            int r = qq >> 3, h = qq & 7;
            const float* av = (is_src ? a_src : a_dst) + (r * 8 + h) * 16;
            const float* wr = W_rel + (size_t)(r * 128 + k) * 128 + h * 16;
            float s = 0.f;
            #pragma unroll
            for (int dd = 0; dd < 16; ++dd) s += wr[dd] * av[dd];
            v = s * LOG2E;   // prescale so agg uses exp2 directly
        } else if (row < 720) {
            int q2 = row - 704;                 // 0..15
            bool is_ts = q2 < 8;
            int h = q2 & 7;
            const float* av = (is_ts ? a_src_lang : a_dst_lang) + h * 16;
            const float* wr = W_self + k * 128 + h * 16;
            float s = 0.f;
            #pragma unroll
            for (int dd = 0; dd < 16; ++dd) s += wr[dd] * av[dd];
            v = s * LOG2E;   // lang self logits, log2-domain
        } else {
            v = 0.f;
        }
        Wt[t] = __float2bfloat16(v);
    } else if (t < 768 * 128 + 144 * 128) {
        int u = t - 768 * 128;
        int n = u >> 7, k = u & 127;
        float v;
        if (n < 128) {
            v = W_cross[k * 128 + n];
        } else {
            int h = n - 128;                    // 0..15
            if (h < 8) {
                const float* av = a_src_lang + h * 16;
                const float* wr = W_cross + k * 128 + h * 16;
                float s = 0.f;
                #pragma unroll
                for (int dd = 0; dd < 16; ++dd) s += wr[dd] * av[dd];
                v = s * LOG2E;                  // ls-vector, log2e-prescaled
            } else {
                v = 0.f;
            }
        }
        Wct[u] = __float2bfloat16(v);
    }

    // --- A pre-conversion: 800000 chunks of 8 f32 -> 8 bf16 ---
    if (t < NN * 16) {
        const float* ap = node_inp + (size_t)t * 8;
        float4 f0 = *(const float4*)ap;
        float4 f1 = *(const float4*)(ap + 4);
        short8 v = (short8){(short)f2us(f0.x), (short)f2us(f0.y),
                            (short)f2us(f0.z), (short)f2us(f0.w),
                            (short)f2us(f1.x), (short)f2us(f1.y),
                            (short)f2us(f1.z), (short)f2us(f1.w)};
        *(short8*)(Ab + (size_t)t * 8) = v;
    }

    // --- bucket store (atomic result consumed as late as possible) ---
    if (t < NE && pos < BCAP)
        bkt[seg * (unsigned)BCAP + (unsigned)pos] = (unsigned short)src;
}

// ---------------------------------------------------------------------------
// MFMA GEMM (64-row x 256-col tiles), grid = (782, 3) — R10-measured manual
// LDS staging (direct-global R7 and DMA R11 variants both regressed).
// Planes: 0: cols 0..255 = Xb rel 0,1; 1: 256..511 = Xb rel 2,3;
//         2: 512..767 = S (wc==0) | es/ed/ts/td + pad (wc==1)
// Wave w covers rows (w&1)*32..+32, cols (w>>1)*128..+128 -> acc[2][8].
// ---------------------------------------------------------------------------
__global__ __launch_bounds__(256) void gemm_node(
    const bf16* __restrict__ Ab,
    const bf16* __restrict__ Bt,
    bf16* __restrict__ outb,
    float* __restrict__ outf,
    unsigned short* __restrict__ es_u,
    unsigned short* __restrict__ ed_u,
    unsigned short* __restrict__ tsd,
    int M)
{
    __shared__ __align__(16) char smem[25600];
    short (*As)[40] = (short (*)[40])smem;            // 64 x 40 shorts
    short (*Bs)[40] = (short (*)[40])(smem + 5120);   // 256 x 40 shorts

    const int tid  = threadIdx.x;
    const int wave = tid >> 6, lane = tid & 63;
    const int quad = lane >> 4, l16 = lane & 15;
    const int wr_ = wave & 1, wc = wave >> 1;         // row-half, col-half
    const int row0 = blockIdx.x * 64;
    const int plane = blockIdx.y;
    const int col0 = plane * 256;

    floatx4 acc[2][8];
    #pragma unroll
    for (int i = 0; i < 2; ++i)
        #pragma unroll
        for (int j = 0; j < 8; ++j) acc[i][j] = (floatx4){0.f, 0.f, 0.f, 0.f};

    for (int k0 = 0; k0 < 128; k0 += 32) {
        // stage A: 64 rows x 32 k -> 256 chunks of 8, 1 per thread (bf16 direct)
        {
            int c = tid;
            int r = c >> 2, off = (c & 3) * 8;
            int gr = row0 + r;
            short8 v = {0, 0, 0, 0, 0, 0, 0, 0};
            if (gr < M)
                v = *(const short8*)(Ab + (((size_t)gr) << 7) + k0 + off);
            *(short8*)&As[r][off] = v;
        }
        // stage B: 256 rows x 32 k -> 1024 chunks, 4 per thread
        #pragma unroll
        for (int i = 0; i < 4; ++i) {
            int c = i * 256 + tid;
            int r = c >> 2, off = (c & 3) * 8;
            short8 w = *(const short8*)(Bt + (((size_t)(col0 + r)) << 7) + k0 + off);
            *(short8*)&Bs[r][off] = w;
        }
        __syncthreads();

        short8 av[2], bv[8];
        #pragma unroll
        for (int mt = 0; mt < 2; ++mt)
            av[mt] = *(const short8*)&As[wr_ * 32 + mt * 16 + l16][quad * 8];
        #pragma unroll
        for (int nt = 0; nt < 8; ++nt)
            bv[nt] = *(const short8*)&Bs[wc * 128 + nt * 16 + l16][quad * 8];
        #pragma unroll
        for (int mt = 0; mt < 2; ++mt)
            #pragma unroll
            for (int nt = 0; nt < 8; ++nt)
                acc[mt][nt] = __builtin_amdgcn_mfma_f32_16x16x32_bf16(
                    av[mt], bv[nt], acc[mt][nt], 0, 0, 0);
        __syncthreads();
    }

    // es/ed/ts/td wave: plane 2, wc==1 -> global cols 640..719 (nt 0..4)
    const bool eswave = (plane == 2 && wc == 1);
    if (eswave) {
        #pragma unroll
        for (int mt = 0; mt < 2; ++mt) {
            #pragma unroll
            for (int reg = 0; reg < 4; ++reg) {
                int gr = row0 + wr_ * 32 + mt * 16 + quad * 4 + reg;
                if (gr >= M) continue;
                #pragma unroll
                for (int nt = 0; nt < 5; ++nt) {
                    int q = nt * 16 + l16;
                    unsigned short v = f2us(acc[mt][nt][reg]);
                    if (q < 32)
                        es_u[(unsigned)((q >> 3) * NN + gr) * 8u + (unsigned)(q & 7)] = v;
                    else if (q < 64)
                        ed_u[(unsigned)(((q - 32) >> 3) * NN + gr) * 8u + (unsigned)((q - 32) & 7)] = v;
                    else
                        tsd[(unsigned)gr * 16u + (unsigned)(q - 64)] = v;
                }
            }
        }
    }

    // LDS-transpose epilogue: wave-private [16][68] f32 region, 64 cols/pass.
    // eswave skips the work but keeps barrier participation uniform.
    float* ct = (float*)(smem + wave * 4352);
    const int rr2 = lane >> 2;
    const int cc0 = (lane & 3) * 16;

    for (int mt = 0; mt < 2; ++mt) {
        #pragma unroll
        for (int half = 0; half < 2; ++half) {
            if (!eswave) {
                #pragma unroll
                for (int nt = 0; nt < 4; ++nt)
                    #pragma unroll
                    for (int reg = 0; reg < 4; ++reg)
                        ct[(quad * 4 + reg) * 68 + nt * 16 + l16] =
                            acc[mt][half * 4 + nt][reg];
            }
            __syncthreads();
            if (!eswave) {
                int gr2 = row0 + wr_ * 32 + mt * 16 + rr2;
                if (gr2 < M) {
                    float4 f0 = *(const float4*)&ct[rr2 * 68 + cc0];
                    float4 f1 = *(const float4*)&ct[rr2 * 68 + cc0 + 4];
                    float4 f2 = *(const float4*)&ct[rr2 * 68 + cc0 + 8];
                    float4 f3 = *(const float4*)&ct[rr2 * 68 + cc0 + 12];
                    int lc = half * 64 + cc0;          // 0..127 within wave block
                    if (plane == 2) {
                        // wc==0 here: S columns (global 512..639) -> f32 out (nt)
                        float* dst = outf + (((size_t)gr2) << 7) + lc;
                        __builtin_nontemporal_store(*(const floatx4*)&f0, (floatx4*)dst);
                        __builtin_nontemporal_store(*(const floatx4*)&f1, (floatx4*)(dst + 4));
                        __builtin_nontemporal_store(*(const floatx4*)&f2, (floatx4*)(dst + 8));
                        __builtin_nontemporal_store(*(const floatx4*)&f3, (floatx4*)(dst + 12));
                    } else {
                        int rel = plane * 2 + wc;
                        float tmp[16] = {f0.x, f0.y, f0.z, f0.w, f1.x, f1.y, f1.z, f1.w,
                                         f2.x, f2.y, f2.z, f2.w, f3.x, f3.y, f3.z, f3.w};
                        short8 o0, o1;
                        #pragma unroll
                        for (int j = 0; j < 8; ++j) o0[j] = (short)f2us(tmp[j]);
                        #pragma unroll
                        for (int j = 0; j < 8; ++j) o1[j] = (short)f2us(tmp[8 + j]);
                        bf16* dst = outb + ((size_t)(rel * NN + gr2) << 7) + lc;
                        *(short8*)dst = o0;
                        *(short8*)(dst + 8) = o1;
                    }
                }
            }
            __syncthreads();
        }
    }
}

// ---------------------------------------------------------------------------
// R12 FUSED aggregation + cross-GEMM + lang softmax. grid = (NN/16, 1).
// Phase 1: each wave aggregates 4 nodes x 4 rels (R4 agg body, bf16
//   round-trip preserved) DIRECTLY into the LDS A-tile As[64][136]
//   (row = node_local*4+rel); validity bytes -> flg[64] in LDS.
//   Eliminates Gb4 write+read (102 MB) + flag traffic + one launch.
// Phase 2: k-loop stages only B (Wct_ext[144][128]); av read from resident
//   As; ls cols 128..143 give lang ls logits (staged via ls_lds alias of Bs).
// ts/td from tsd[NN][16]; epilogue has no cross-lane reductions.
// ---------------------------------------------------------------------------
__global__ __launch_bounds__(256) void agg_lang(
    const unsigned short* __restrict__ bkt, const int* __restrict__ counts,
    const bf16* __restrict__ Xb, const unsigned short* __restrict__ es_u,
    const unsigned short* __restrict__ ed_u, const float* __restrict__ bias_rel,
    const bf16* __restrict__ Bt,
    const unsigned short* __restrict__ tsd,
    const float* __restrict__ bias_lang,
    float* __restrict__ out)
{
    __shared__ __align__(16) char smem[29056];
    short (*As)[136] = (short (*)[136])smem;                 // 64 x 136 = 17408 B
    short (*Bs)[40]  = (short (*)[40])(smem + 17408);        // 144 x 40 = 11520 B
    float (*ls_lds)[4][9] = (float (*)[4][9])(smem + 17408); // aliases Bs post-GEMM
    unsigned char* flg = (unsigned char*)(smem + 28928);     // 64 B validity

    const int tid  = threadIdx.x;
    const int wave = tid >> 6, lane = tid & 63;
    const int quad = lane >> 4, l16 = lane & 15;
    const int wr_ = wave & 1, wc = wave >> 1;
    const int node0 = blockIdx.x * 16;

    // --- prefetch Sv / ts / td with phase-2 indexing (hides under phase 1) ---
    float svp[2][4];
    float tsv[2][4], tdv[2][4];
    #pragma unroll
    for (int mt = 0; mt < 2; ++mt) {
        int node = node0 + wr_ * 8 + mt * 4 + quad;
        #pragma unroll
        for (int nt = 0; nt < 4; ++nt) {
            int hh = wc * 4 + nt;
            svp[mt][nt] = out[(unsigned)node * 128u + (unsigned)(wc * 64 + nt * 16 + l16)];
            tsv[mt][nt] = us2f(tsd[(unsigned)node * 16u + (unsigned)hh]);
            tdv[mt][nt] = us2f(tsd[(unsigned)node * 16u + 8u + (unsigned)hh]);
        }
    }

    // =================== Phase 1: aggregate into As ===================
    {
        const int nl4 = lane >> 4;                 // node within wave group
        const int f0  = l16 * 8;                   // col start (8 cols, 16B)
        const int h   = l16 >> 1;                  // head of this col block
        const int node = node0 + wave * 4 + nl4;   // < NN (NN/16 exact)
        const int lrow = (wave * 4 + nl4) * 4;     // local row base

        for (int rel = 0; rel < 4; ++rel) {
            const unsigned seg = (unsigned)(rel * NN + node);
            int cnt = counts[seg];
            cnt = cnt < BCAP ? cnt : BCAP;
            const unsigned short* bk = bkt + seg * (unsigned)BCAP;
            const float edv = us2f(ed_u[seg * 8u + (unsigned)h]);
            const unsigned short* Xr  = (const unsigned short*)Xb +
                                        (size_t)rel * (size_t)(NN * 128);
            const unsigned short* esr = es_u + (unsigned)rel * (unsigned)(NN * 8);

            float a[8];
            #pragma unroll
            for (int j = 0; j < 8; ++j) a[j] = 0.f;
            float den = 0.f;

            int e = 0;
            for (; e + 1 < cnt; e += 2) {
                unsigned pair = *(const unsigned*)(bk + e);
                int s0 = (int)(pair & 0xFFFFu);
                int s1 = (int)(pair >> 16);
                float e0 = us2f(esr[(unsigned)s0 * 8u + (unsigned)h]);
                float e1 = us2f(esr[(unsigned)s1 * 8u + (unsigned)h]);
                short8 u0 = *(const short8*)(Xr + (size_t)s0 * 128 + f0);
                short8 u1 = *(const short8*)(Xr + (size_t)s1 * 128 + f0);
                float aa0 = e0 + edv, aa1 = e1 + edv;
                float w0 = __builtin_amdgcn_exp2f(fmaxf(aa0, 0.2f * aa0));
                float w1 = __builtin_amdgcn_exp2f(fmaxf(aa1, 0.2f * aa1));
                #pragma unroll
                for (int j = 0; j < 8; ++j)
                    a[j] += w0 * us2f((unsigned short)u0[j]) +
                            w1 * us2f((unsigned short)u1[j]);
                den += w0 + w1;
            }
            if (e < cnt) {
                int s0 = (int)bk[e];
                float e0 = us2f(esr[(unsigned)s0 * 8u + (unsigned)h]);
                short8 u0 = *(const short8*)(Xr + (size_t)s0 * 128 + f0);
                float aa0 = e0 + edv;
                float w0 = __builtin_amdgcn_exp2f(fmaxf(aa0, 0.2f * aa0));
                #pragma unroll
                for (int j = 0; j < 8; ++j) a[j] += w0 * us2f((unsigned short)u0[j]);
                den += w0;
            }

            float inv = den > 0.f ? __builtin_amdgcn_rcpf(den) : 0.f;
            const float* bp = bias_rel + rel * 128 + f0;
            float4 b0 = *(const float4*)bp;
            float4 b1 = *(const float4*)(bp + 4);
            float bb[8] = {b0.x, b0.y, b0.z, b0.w, b1.x, b1.y, b1.z, b1.w};
            short8 o;
            #pragma unroll
            for (int j = 0; j < 8; ++j)
                o[j] = (short)f2us(gelu_f(__builtin_fmaf(a[j], inv, bb[j])));
            *(short8*)&As[lrow + rel][f0] = o;       // bf16 round-trip == Gb4 path
            if (l16 == 0) flg[lrow + rel] = (unsigned char)(cnt > 0);
        }
    }
    __syncthreads();

    // =================== Phase 2: cross-GEMM + lang softmax ===================
    floatx4 acc[2][4];
    floatx4 accl[2];
    #pragma unroll
    for (int i = 0; i < 2; ++i) {
        #pragma unroll
        for (int j = 0; j < 4; ++j) acc[i][j] = (floatx4){0.f, 0.f, 0.f, 0.f};
        accl[i] = (floatx4){0.f, 0.f, 0.f, 0.f};
    }

    for (int k0 = 0; k0 < 128; k0 += 32) {
        // stage B: 144 rows x 32 k -> 576 chunks, 3 per thread (guarded)
        #pragma unroll
        for (int i = 0; i < 3; ++i) {
            int c = i * 256 + tid;
            if (c < 576) {
                int r = c >> 2, off = (c & 3) * 8;
                short8 w = *(const short8*)(Bt + (((size_t)r) << 7) + k0 + off);
                *(short8*)&Bs[r][off] = w;
            }
        }
        __syncthreads();

        short8 av[2], bv[4], bvl;
        #pragma unroll
        for (int mt = 0; mt < 2; ++mt)
            av[mt] = *(const short8*)&As[wr_ * 32 + mt * 16 + l16][k0 + quad * 8];
        #pragma unroll
        for (int nt = 0; nt < 4; ++nt)
            bv[nt] = *(const short8*)&Bs[wc * 64 + nt * 16 + l16][quad * 8];
        // 5th tile (ls cols 128..143) — row wc*64+64+l16 <= 143, always valid
        bvl = *(const short8*)&Bs[wc * 64 + 64 + l16][quad * 8];
        #pragma unroll
        for (int mt = 0; mt < 2; ++mt) {
            #pragma unroll
            for (int nt = 0; nt < 4; ++nt)
                acc[mt][nt] = __builtin_amdgcn_mfma_f32_16x16x32_bf16(
                    av[mt], bv[nt], acc[mt][nt], 0, 0, 0);
            if (wc)   // wave-uniform; static acc index -> stays in registers
                accl[mt] = __builtin_amdgcn_mfma_f32_16x16x32_bf16(
                    av[mt], bvl, accl[mt], 0, 0, 0);
        }
        __syncthreads();
    }

    // --- stage ls logits to LDS (wc=1, cols 128..135 -> l16 = head) ---
    if (wc == 1 && l16 < 8) {
        #pragma unroll
        for (int mt = 0; mt < 2; ++mt) {
            int nl = wr_ * 8 + mt * 4 + quad;
            #pragma unroll
            for (int reg = 0; reg < 4; ++reg)
                ls_lds[nl][reg][l16] = accl[mt][reg];
        }
    }
    __syncthreads();

    // --- epilogue: softmax over {self} U {4 rels}, per (node, col) ---
    #pragma unroll
    for (int nt = 0; nt < 4; ++nt) {
        int col = wc * 64 + nt * 16 + l16;
        float bl = bias_lang[col];
        int hh = wc * 4 + nt;                    // head of this col-tile
        #pragma unroll
        for (int mt = 0; mt < 2; ++mt) {
            int nl = wr_ * 8 + mt * 4 + quad;
            int node = node0 + nl;
            float Sv = svp[mt][nt];
            float ts = tsv[mt][nt];
            float td = tdv[mt][nt];
            float g0 = ls_lds[nl][0][hh] + td;
            float g1 = ls_lds[nl][1][hh] + td;
            float g2 = ls_lds[nl][2][hh] + td;
            float g3 = ls_lds[nl][3][hh] + td;
            float aS = ts + td;
            float lS = fmaxf(aS, 0.2f * aS);
            float l0 = fmaxf(g0, 0.2f * g0);
            float l1 = fmaxf(g1, 0.2f * g1);
            float l2 = fmaxf(g2, 0.2f * g2);
            float l3 = fmaxf(g3, 0.2f * g3);
            unsigned fl = *(const unsigned*)(flg + nl * 4);
            bool v0 = (fl & 0x000000FFu) != 0, v1 = (fl & 0x0000FF00u) != 0;
            bool v2 = (fl & 0x00FF0000u) != 0, v3 = (fl & 0xFF000000u) != 0;
            float m = lS;
            if (v0) m = fmaxf(m, l0);
            if (v1) m = fmaxf(m, l1);
            if (v2) m = fmaxf(m, l2);
            if (v3) m = fmaxf(m, l3);
            float eS = __builtin_amdgcn_exp2f(lS - m);
            float e0 = v0 ? __builtin_amdgcn_exp2f(l0 - m) : 0.f;
            float e1 = v1 ? __builtin_amdgcn_exp2f(l1 - m) : 0.f;
            float e2 = v2 ? __builtin_amdgcn_exp2f(l2 - m) : 0.f;
            float e3 = v3 ? __builtin_amdgcn_exp2f(l3 - m) : 0.f;
            float sum = eS + e0 + e1 + e2 + e3;
            float o = eS * Sv + e0 * acc[mt][nt][0] + e1 * acc[mt][nt][1] +
                      e2 * acc[mt][nt][2] + e3 * acc[mt][nt][3];
            o = o / sum + bl;
            __builtin_nontemporal_store(o, &out[(unsigned)node * 128u + (unsigned)col]);
        }
    }
}

// ---------------------------------------------------------------------------
extern "C" void kernel_launch(void* const* d_in, const int* in_sizes, int n_in,
                              void* d_out, int out_size, void* d_ws, size_t ws_size,
                              hipStream_t stream) {
    const float* node_inp     = (const float*)d_in[0];
    const int*   edge_index   = (const int*)d_in[1];
    const int*   edge_type    = (const int*)d_in[2];
    const float* W_rel        = (const float*)d_in[3];
    const float* att_src_rel  = (const float*)d_in[4];
    const float* att_dst_rel  = (const float*)d_in[5];
    const float* bias_rel     = (const float*)d_in[6];
    const float* W_self       = (const float*)d_in[7];
    const float* W_cross      = (const float*)d_in[8];
    const float* att_src_lang = (const float*)d_in[9];
    const float* att_dst_lang = (const float*)d_in[10];
    const float* bias_lang    = (const float*)d_in[11];
    (void)in_sizes; (void)n_in;

    // workspace layout (bytes) — total 78,633,472 (Gb4/flag eliminated by fusion)
    const size_t SZ_XB   = (size_t)NREL * NN * 128 * 2;   // 51,200,000 (bf16)
    const size_t SZ_ES   = (size_t)NREL * NN * 8 * 2;     //  3,200,000 (bf16)
    const size_t SZ_TSD  = (size_t)NN * 16 * 2;           //  1,600,000 (bf16)
    const size_t SZ_AB   = (size_t)NN * 128 * 2;          // 12,800,000 (bf16)
    const size_t SZ_WT   = 768 * 128 * 2;                 //    196,608
    const size_t SZ_WCT  = 144 * 128 * 2;                 //     36,864 (ext: +ls rows)
    const size_t SZ_BKT  = (size_t)NSEG * BCAP * 2;       //  8,800,000 (uint16 buckets)
    const size_t SZ_CNT  = (size_t)NSEG * 4;              //    800,000
    const size_t TOTAL = SZ_XB + 2 * SZ_ES + SZ_TSD + SZ_AB + SZ_WT + SZ_WCT +
                         SZ_BKT + SZ_CNT;

    if (ws_size < TOTAL) {
        fill_kernel<<<(out_size + 255) / 256, 256, 0, stream>>>((float*)d_out, out_size);
        return;
    }

    char* ws = (char*)d_ws;
    size_t o = 0;
    bf16*  Xb      = (bf16*)(ws + o);  o += SZ_XB;
    unsigned short* es_u = (unsigned short*)(ws + o); o += SZ_ES;
    unsigned short* ed_u = (unsigned short*)(ws + o); o += SZ_ES;
    unsigned short* tsd  = (unsigned short*)(ws + o); o += SZ_TSD;
    bf16*  Ab      = (bf16*)(ws + o);  o += SZ_AB;
    bf16*  Wt      = (bf16*)(ws + o);  o += SZ_WT;
    bf16*  Wct     = (bf16*)(ws + o);  o += SZ_WCT;
    unsigned short* bkt = (unsigned short*)(ws + o); o += SZ_BKT;
    int*   counts  = (int*)(ws + o);   o += SZ_CNT;
    float* S       = (float*)d_out;  // S scratch in d_out; agg_lang overwrites

    // zero bucket counters (graph-capturable memset node)
    hipMemsetAsync(counts, 0, SZ_CNT, stream);

    // fused prep (weights + Ab convert) + 1-edge-per-thread bucket scatter
    prep_scatter<<<(NE + 255) / 256, 256, 0, stream>>>(
        W_rel, W_self, W_cross, att_src_rel, att_dst_rel, att_src_lang,
        att_dst_lang, node_inp, edge_index, edge_type, Wt, Wct, Ab, counts, bkt);

    // 3x 256-wide GEMM planes (R10-measured manual LDS staging)
    dim3 g1((NN + 63) / 64, 3);
    gemm_node<<<g1, 256, 0, stream>>>(Ab, Wt, Xb, S, es_u, ed_u, tsd, NN);

    // FUSED aggregation + cross-GEMM + lang softmax -> d_out
    agg_lang<<<NN / 16, 256, 0, stream>>>(bkt, counts, Xb, es_u, ed_u, bias_rel,
                                          Wct, tsd, bias_lang, (float*)d_out);
}

// Round 14
// 264.903 us; speedup vs baseline: 1.0508x; 1.0508x over previous
//
#include <hip/hip_runtime.h>
#include <hip/hip_bf16.h>
#include <math.h>

#define NN 50000
#define NE 800000
#define NREL 4
#define NHEAD 8
#define NSEG (NREL * NN)            // 200000 (rel,dst) segments
#define BCAP 22                     // bucket capacity (Poisson(4) tail ~5e-11)

typedef __hip_bfloat16 bf16;
typedef short short8 __attribute__((ext_vector_type(8)));
typedef float floatx4 __attribute__((ext_vector_type(4)));

#define LOG2E 1.4426950408889634f

__device__ __forceinline__ float b2f(bf16 v) { return __bfloat162float(v); }
__device__ __forceinline__ float us2f(unsigned short u) {
    return __uint_as_float(((unsigned)u) << 16);
}
__device__ __forceinline__ unsigned short f2us(float v) {
    bf16 b = __float2bfloat16(v);
    return *(unsigned short*)&b;
}

// Exact-enough GELU: erf via Abramowitz-Stegun 7.1.26 (|err| <= 1.5e-7).
__device__ __forceinline__ float gelu_f(float v) {
    float z = v * 0.70710678118654752f;
    float az = fabsf(z);
    float t = __builtin_amdgcn_rcpf(__builtin_fmaf(0.3275911f, az, 1.f));
    float p = t * (0.254829592f +
              t * (-0.284496736f +
              t * (1.421413741f +
              t * (-1.453152027f +
              t * 1.061405429f))));
    float ex = __builtin_amdgcn_exp2f(az * az * -LOG2E);
    float er = copysignf(1.f - p * ex, z);
    return 0.5f * v * (1.f + er);
}

// ---------------------------------------------------------------------------
// Diagnostic: fill out with 1000.0 when ws_size is insufficient
// ---------------------------------------------------------------------------
__global__ void fill_kernel(float* __restrict__ out, int n) {
    int t = blockIdx.x * blockDim.x + threadIdx.x;
    if (t < n) out[t] = 1000.0f;
}

// ---------------------------------------------------------------------------
// Fused prep + edge scatter. 800000 threads (== NE, == NN*16).
// Wt[768][128]: rows 0..511 W_rel, 512..639 W_self, 640..671 es-vectors,
//               672..703 ed-vectors, 704..711 ts-vectors (log2e*W_self@asl_h),
//               712..719 td-vectors (log2e*W_self@adl_h), 720..767 zero.
// Wct_ext[144][128]: rows 0..127 W_cross^T; rows 128..135 ls-vectors
//               (log2e * W_cross @ att_src_lang per head); 136..143 zero.
// ---------------------------------------------------------------------------
__global__ __launch_bounds__(256) void prep_scatter(
    const float* __restrict__ W_rel,
    const float* __restrict__ W_self,
    const float* __restrict__ W_cross,
    const float* __restrict__ a_src,
    const float* __restrict__ a_dst,
    const float* __restrict__ a_src_lang,
    const float* __restrict__ a_dst_lang,
    const float* __restrict__ node_inp,
    const int* __restrict__ ei,
    const int* __restrict__ et,
    bf16* __restrict__ Wt, bf16* __restrict__ Wct,
    bf16* __restrict__ Ab,
    int* __restrict__ counts,
    unsigned short* __restrict__ bkt) {
    int t = blockIdx.x * blockDim.x + threadIdx.x;

    // --- edge scatter: issue the atomic as early as possible ---
    int src = 0, pos = BCAP;
    unsigned seg = 0;
    if (t < NE) {
        src = ei[t];
        int dst = ei[NE + t];
        seg = (unsigned)(et[t] * NN + dst);
        pos = atomicAdd(&counts[seg], 1);
    }

    // --- weight packs (small head of the grid) ---
    if (t < 768 * 128) {
        int row = t >> 7, k = t & 127;
        float v;
        if (row < 512) {
            int r = row >> 7, c = row & 127;
            v = W_rel[(r * 128 + k) * 128 + c];
        } else if (row < 640) {
            v = W_self[k * 128 + (row - 512)];
        } else if (row < 704) {
            int q = row - 640;
            bool is_src = q < 32;
            int qq = is_src ? q : q - 32;
            int r = qq >> 3, h = qq & 7;
            const float* av = (is_src ? a_src : a_dst) + (r * 8 + h) * 16;
            const float* wr = W_rel + (size_t)(r * 128 + k) * 128 + h * 16;
            float s = 0.f;
            #pragma unroll
            for (int dd = 0; dd < 16; ++dd) s += wr[dd] * av[dd];
            v = s * LOG2E;   // prescale so agg uses exp2 directly
        } else if (row < 720) {
            int q2 = row - 704;                 // 0..15
            bool is_ts = q2 < 8;
            int h = q2 & 7;
            const float* av = (is_ts ? a_src_lang : a_dst_lang) + h * 16;
            const float* wr = W_self + k * 128 + h * 16;
            float s = 0.f;
            #pragma unroll
            for (int dd = 0; dd < 16; ++dd) s += wr[dd] * av[dd];
            v = s * LOG2E;   // lang self logits, log2-domain
        } else {
            v = 0.f;
        }
        Wt[t] = __float2bfloat16(v);
    } else if (t < 768 * 128 + 144 * 128) {
        int u = t - 768 * 128;
        int n = u >> 7, k = u & 127;
        float v;
        if (n < 128) {
            v = W_cross[k * 128 + n];
        } else {
            int h = n - 128;                    // 0..15
            if (h < 8) {
                const float* av = a_src_lang + h * 16;
                const float* wr = W_cross + k * 128 + h * 16;
                float s = 0.f;
                #pragma unroll
                for (int dd = 0; dd < 16; ++dd) s += wr[dd] * av[dd];
                v = s * LOG2E;                  // ls-vector, log2e-prescaled
            } else {
                v = 0.f;
            }
        }
        Wct[u] = __float2bfloat16(v);
    }

    // --- A pre-conversion: 800000 chunks of 8 f32 -> 8 bf16 ---
    if (t < NN * 16) {
        const float* ap = node_inp + (size_t)t * 8;
        float4 f0 = *(const float4*)ap;
        float4 f1 = *(const float4*)(ap + 4);
        short8 v = (short8){(short)f2us(f0.x), (short)f2us(f0.y),
                            (short)f2us(f0.z), (short)f2us(f0.w),
                            (short)f2us(f1.x), (short)f2us(f1.y),
                            (short)f2us(f1.z), (short)f2us(f1.w)};
        *(short8*)(Ab + (size_t)t * 8) = v;
    }

    // --- bucket store (atomic result consumed as late as possible) ---
    if (t < NE && pos < BCAP)
        bkt[seg * (unsigned)BCAP + (unsigned)pos] = (unsigned short)src;
}

// ---------------------------------------------------------------------------
// MFMA GEMM (64-row x 256-col tiles), grid = (782, 3) — R10-measured manual
// LDS staging; R13: epilogue barriers REMOVED (ct is wave-private; k-loop's
// final barrier already fences As/Bs reads; intra-wave ds ordering is
// compiler-guaranteed via lgkmcnt). eswave exits after its global stores.
// Planes: 0: cols 0..255 = Xb rel 0,1; 1: 256..511 = Xb rel 2,3;
//         2: 512..767 = S (wc==0) | es/ed/ts/td + pad (wc==1)
// Wave w covers rows (w&1)*32..+32, cols (w>>1)*128..+128 -> acc[2][8].
// ---------------------------------------------------------------------------
__global__ __launch_bounds__(256) void gemm_node(
    const bf16* __restrict__ Ab,
    const bf16* __restrict__ Bt,
    bf16* __restrict__ outb,
    float* __restrict__ outf,
    unsigned short* __restrict__ es_u,
    unsigned short* __restrict__ ed_u,
    unsigned short* __restrict__ tsd,
    int M)
{
    __shared__ __align__(16) char smem[25600];
    short (*As)[40] = (short (*)[40])smem;            // 64 x 40 shorts
    short (*Bs)[40] = (short (*)[40])(smem + 5120);   // 256 x 40 shorts

    const int tid  = threadIdx.x;
    const int wave = tid >> 6, lane = tid & 63;
    const int quad = lane >> 4, l16 = lane & 15;
    const int wr_ = wave & 1, wc = wave >> 1;         // row-half, col-half
    const int row0 = blockIdx.x * 64;
    const int plane = blockIdx.y;
    const int col0 = plane * 256;

    floatx4 acc[2][8];
    #pragma unroll
    for (int i = 0; i < 2; ++i)
        #pragma unroll
        for (int j = 0; j < 8; ++j) acc[i][j] = (floatx4){0.f, 0.f, 0.f, 0.f};

    for (int k0 = 0; k0 < 128; k0 += 32) {
        // stage A: 64 rows x 32 k -> 256 chunks of 8, 1 per thread (bf16 direct)
        {
            int c = tid;
            int r = c >> 2, off = (c & 3) * 8;
            int gr = row0 + r;
            short8 v = {0, 0, 0, 0, 0, 0, 0, 0};
            if (gr < M)
                v = *(const short8*)(Ab + (((size_t)gr) << 7) + k0 + off);
            *(short8*)&As[r][off] = v;
        }
        // stage B: 256 rows x 32 k -> 1024 chunks, 4 per thread
        #pragma unroll
        for (int i = 0; i < 4; ++i) {
            int c = i * 256 + tid;
            int r = c >> 2, off = (c & 3) * 8;
            short8 w = *(const short8*)(Bt + (((size_t)(col0 + r)) << 7) + k0 + off);
            *(short8*)&Bs[r][off] = w;
        }
        __syncthreads();

        short8 av[2], bv[8];
        #pragma unroll
        for (int mt = 0; mt < 2; ++mt)
            av[mt] = *(const short8*)&As[wr_ * 32 + mt * 16 + l16][quad * 8];
        #pragma unroll
        for (int nt = 0; nt < 8; ++nt)
            bv[nt] = *(const short8*)&Bs[wc * 128 + nt * 16 + l16][quad * 8];
        #pragma unroll
        for (int mt = 0; mt < 2; ++mt)
            #pragma unroll
            for (int nt = 0; nt < 8; ++nt)
                acc[mt][nt] = __builtin_amdgcn_mfma_f32_16x16x32_bf16(
                    av[mt], bv[nt], acc[mt][nt], 0, 0, 0);
        __syncthreads();   // final iteration: fences all As/Bs reads block-wide
    }

    // es/ed/ts/td wave: plane 2, wc==1 -> global cols 640..719 (nt 0..4)
    if (plane == 2 && wc == 1) {
        #pragma unroll
        for (int mt = 0; mt < 2; ++mt) {
            #pragma unroll
            for (int reg = 0; reg < 4; ++reg) {
                int gr = row0 + wr_ * 32 + mt * 16 + quad * 4 + reg;
                if (gr >= M) continue;
                #pragma unroll
                for (int nt = 0; nt < 5; ++nt) {
                    int q = nt * 16 + l16;
                    unsigned short v = f2us(acc[mt][nt][reg]);
                    if (q < 32)
                        es_u[(unsigned)((q >> 3) * NN + gr) * 8u + (unsigned)(q & 7)] = v;
                    else if (q < 64)
                        ed_u[(unsigned)(((q - 32) >> 3) * NN + gr) * 8u + (unsigned)((q - 32) & 7)] = v;
                    else
                        tsd[(unsigned)gr * 16u + (unsigned)(q - 64)] = v;
                }
            }
        }
        return;   // no barriers below -> safe to exit
    }

    // LDS-transpose epilogue: wave-private [16][68] f32 region, 64 cols/pass.
    // Barrier-free: ct regions are disjoint per wave; intra-wave ds_write ->
    // ds_read ordering handled by compiler-inserted lgkmcnt waits.
    float* ct = (float*)(smem + wave * 4352);
    const int rr2 = lane >> 2;
    const int cc0 = (lane & 3) * 16;
    const int gr2base = row0 + wr_ * 32 + rr2;

    for (int mt = 0; mt < 2; ++mt) {
        #pragma unroll
        for (int half = 0; half < 2; ++half) {
            #pragma unroll
            for (int nt = 0; nt < 4; ++nt)
                #pragma unroll
                for (int reg = 0; reg < 4; ++reg)
                    ct[(quad * 4 + reg) * 68 + nt * 16 + l16] =
                        acc[mt][half * 4 + nt][reg];
            int gr2 = gr2base + mt * 16;
            if (gr2 < M) {
                float4 f0 = *(const float4*)&ct[rr2 * 68 + cc0];
                float4 f1 = *(const float4*)&ct[rr2 * 68 + cc0 + 4];
                float4 f2 = *(const float4*)&ct[rr2 * 68 + cc0 + 8];
                float4 f3 = *(const float4*)&ct[rr2 * 68 + cc0 + 12];
                int lc = half * 64 + cc0;          // 0..127 within wave block
                if (plane == 2) {
                    // wc==0 here: S columns (global 512..639) -> f32 out (nt)
                    float* dst = outf + (((size_t)gr2) << 7) + lc;
                    __builtin_nontemporal_store(*(const floatx4*)&f0, (floatx4*)dst);
                    __builtin_nontemporal_store(*(const floatx4*)&f1, (floatx4*)(dst + 4));
                    __builtin_nontemporal_store(*(const floatx4*)&f2, (floatx4*)(dst + 8));
                    __builtin_nontemporal_store(*(const floatx4*)&f3, (floatx4*)(dst + 12));
                } else {
                    int rel = plane * 2 + wc;
                    float tmp[16] = {f0.x, f0.y, f0.z, f0.w, f1.x, f1.y, f1.z, f1.w,
                                     f2.x, f2.y, f2.z, f2.w, f3.x, f3.y, f3.z, f3.w};
                    short8 o0, o1;
                    #pragma unroll
                    for (int j = 0; j < 8; ++j) o0[j] = (short)f2us(tmp[j]);
                    #pragma unroll
                    for (int j = 0; j < 8; ++j) o1[j] = (short)f2us(tmp[8 + j]);
                    bf16* dst = outb + ((size_t)(rel * NN + gr2) << 7) + lc;
                    *(short8*)dst = o0;
                    *(short8*)(dst + 8) = o1;
                }
            }
        }
    }
}

// ---------------------------------------------------------------------------
// Batched aggregation (R4 restructure): 4 segments per wave.
// grid = (NN/16, NREL); block 256 = 4 waves; wave covers 4 nodes.
// ---------------------------------------------------------------------------
__global__ __launch_bounds__(256) void agg_kernel(
    const unsigned short* __restrict__ bkt, const int* __restrict__ counts,
    const bf16* __restrict__ Xb, const unsigned short* __restrict__ es_u,
    const unsigned short* __restrict__ ed_u, const float* __restrict__ bias_rel,
    bf16* __restrict__ Gb4, unsigned char* __restrict__ flag)
{
    const int rel  = blockIdx.y;
    const int wave = threadIdx.x >> 6, l = threadIdx.x & 63;
    const int n    = blockIdx.x * 16 + wave * 4 + (l >> 4);   // NN/16 exact
    const int l16  = l & 15;
    const int f0   = l16 * 8;            // col start (8 cols, 16B)
    const int h    = l16 >> 1;           // head of this col block

    const unsigned seg = (unsigned)(rel * NN + n);
    int cnt = counts[seg];
    cnt = cnt < BCAP ? cnt : BCAP;
    const unsigned short* bk  = bkt + seg * (unsigned)BCAP;   // 44B rows, 4B-aligned
    const float edv = us2f(ed_u[seg * 8u + (unsigned)h]);
    const unsigned short* Xr  = (const unsigned short*)Xb +
                                (size_t)rel * (size_t)(NN * 128);
    const unsigned short* esr = es_u + (unsigned)rel * (unsigned)(NN * 8);

    float a[8];
    #pragma unroll
    for (int j = 0; j < 8; ++j) a[j] = 0.f;
    float den = 0.f;

    int e = 0;
    for (; e + 1 < cnt; e += 2) {
        unsigned pair = *(const unsigned*)(bk + e);           // bk[e], bk[e+1]
        int s0 = (int)(pair & 0xFFFFu);
        int s1 = (int)(pair >> 16);
        float e0 = us2f(esr[(unsigned)s0 * 8u + (unsigned)h]);
        float e1 = us2f(esr[(unsigned)s1 * 8u + (unsigned)h]);
        short8 u0 = *(const short8*)(Xr + (size_t)s0 * 128 + f0);
        short8 u1 = *(const short8*)(Xr + (size_t)s1 * 128 + f0);
        float aa0 = e0 + edv, aa1 = e1 + edv;
        float w0 = __builtin_amdgcn_exp2f(fmaxf(aa0, 0.2f * aa0));
        float w1 = __builtin_amdgcn_exp2f(fmaxf(aa1, 0.2f * aa1));
        #pragma unroll
        for (int j = 0; j < 8; ++j)
            a[j] += w0 * us2f((unsigned short)u0[j]) +
                    w1 * us2f((unsigned short)u1[j]);
        den += w0 + w1;
    }
    if (e < cnt) {
        int s0 = (int)bk[e];
        float e0 = us2f(esr[(unsigned)s0 * 8u + (unsigned)h]);
        short8 u0 = *(const short8*)(Xr + (size_t)s0 * 128 + f0);
        float aa0 = e0 + edv;
        float w0 = __builtin_amdgcn_exp2f(fmaxf(aa0, 0.2f * aa0));
        #pragma unroll
        for (int j = 0; j < 8; ++j) a[j] += w0 * us2f((unsigned short)u0[j]);
        den += w0;
    }

    float inv = den > 0.f ? __builtin_amdgcn_rcpf(den) : 0.f;
    const float* bp = bias_rel + rel * 128 + f0;
    float4 b0 = *(const float4*)bp;
    float4 b1 = *(const float4*)(bp + 4);
    float bb[8] = {b0.x, b0.y, b0.z, b0.w, b1.x, b1.y, b1.z, b1.w};
    short8 o;
    #pragma unroll
    for (int j = 0; j < 8; ++j)
        o[j] = (short)f2us(gelu_f(__builtin_fmaf(a[j], inv, bb[j])));
    __builtin_nontemporal_store(o, (short8*)((unsigned short*)Gb4 +
        ((size_t)((unsigned)n * 4u + (unsigned)rel)) * 128u + (unsigned)f0));
    if (l16 == 0)
        flag[(unsigned)n * 4u + (unsigned)rel] = (unsigned char)(cnt > 0);
}

// ---------------------------------------------------------------------------
// Fused cross-GEMM + lang softmax: B = Wct_ext[144][128].
// ts/td (lang self logits per node,head) are precomputed by gemm_node into
// tsd[NN][16] bf16 -> epilogue has NO cross-lane reductions at all.
// ---------------------------------------------------------------------------
__global__ __launch_bounds__(256) void gemm_lang(
    const bf16* __restrict__ A,
    const bf16* __restrict__ Bt,
    const unsigned char* __restrict__ flag,
    const unsigned short* __restrict__ tsd,
    const float* __restrict__ bias_lang,
    float* __restrict__ out)
{
    __shared__ __align__(16) char smem[16640];
    short (*As)[40] = (short (*)[40])smem;            // 64 x 40
    short (*Bs)[40] = (short (*)[40])(smem + 5120);   // 144 x 40
    float (*ls_lds)[4][9] = (float (*)[4][9])smem;    // aliases As post-GEMM

    const int M = NN * NREL;
    const int tid  = threadIdx.x;
    const int wave = tid >> 6, lane = tid & 63;
    const int quad = lane >> 4, l16 = lane & 15;
    const int wr_ = wave & 1, wc = wave >> 1;
    const int row0 = blockIdx.x * 64;
    const int node0 = blockIdx.x * 16;

    // --- prefetch Sv (8), flag words (2), ts/td (16) ---
    float svp[2][4];
    unsigned flw[2];
    float tsv[2][4], tdv[2][4];
    #pragma unroll
    for (int mt = 0; mt < 2; ++mt) {
        int node = node0 + wr_ * 8 + mt * 4 + quad;
        flw[mt] = *(const unsigned*)(flag + (unsigned)node * 4u);
        #pragma unroll
        for (int nt = 0; nt < 4; ++nt) {
            int hh = wc * 4 + nt;
            svp[mt][nt] = out[(unsigned)node * 128u + (unsigned)(wc * 64 + nt * 16 + l16)];
            tsv[mt][nt] = us2f(tsd[(unsigned)node * 16u + (unsigned)hh]);
            tdv[mt][nt] = us2f(tsd[(unsigned)node * 16u + 8u + (unsigned)hh]);
        }
    }

    floatx4 acc[2][4];
    floatx4 accl[2];
    #pragma unroll
    for (int i = 0; i < 2; ++i) {
        #pragma unroll
        for (int j = 0; j < 4; ++j) acc[i][j] = (floatx4){0.f, 0.f, 0.f, 0.f};
        accl[i] = (floatx4){0.f, 0.f, 0.f, 0.f};
    }

    for (int k0 = 0; k0 < 128; k0 += 32) {
        {
            int c = tid;
            int r = c >> 2, off = (c & 3) * 8;
            int gr = row0 + r;
            short8 v = {0, 0, 0, 0, 0, 0, 0, 0};
            if (gr < M)
                v = *(const short8*)(A + (((size_t)gr) << 7) + k0 + off);
            *(short8*)&As[r][off] = v;
        }
        // stage B: 144 rows x 32 k -> 576 chunks, 3 per thread (guarded)
        #pragma unroll
        for (int i = 0; i < 3; ++i) {
            int c = i * 256 + tid;
            if (c < 576) {
                int r = c >> 2, off = (c & 3) * 8;
                short8 w = *(const short8*)(Bt + (((size_t)r) << 7) + k0 + off);
                *(short8*)&Bs[r][off] = w;
            }
        }
        __syncthreads();

        short8 av[2], bv[4], bvl;
        #pragma unroll
        for (int mt = 0; mt < 2; ++mt)
            av[mt] = *(const short8*)&As[wr_ * 32 + mt * 16 + l16][quad * 8];
        #pragma unroll
        for (int nt = 0; nt < 4; ++nt)
            bv[nt] = *(const short8*)&Bs[wc * 64 + nt * 16 + l16][quad * 8];
        // 5th tile (ls cols 128..143) — row wc*64+64+l16 <= 143, always valid
        bvl = *(const short8*)&Bs[wc * 64 + 64 + l16][quad * 8];
        #pragma unroll
        for (int mt = 0; mt < 2; ++mt) {
            #pragma unroll
            for (int nt = 0; nt < 4; ++nt)
                acc[mt][nt] = __builtin_amdgcn_mfma_f32_16x16x32_bf16(
                    av[mt], bv[nt], acc[mt][nt], 0, 0, 0);
            if (wc)   // wave-uniform; static acc index -> stays in registers
                accl[mt] = __builtin_amdgcn_mfma_f32_16x16x32_bf16(
                    av[mt], bvl, accl[mt], 0, 0, 0);
        }
        __syncthreads();
    }

    // --- stage ls logits to LDS (wc=1, cols 128..135 -> l16 = head) ---
    if (wc == 1 && l16 < 8) {
        #pragma unroll
        for (int mt = 0; mt < 2; ++mt) {
            int nl = wr_ * 8 + mt * 4 + quad;
            #pragma unroll
            for (int reg = 0; reg < 4; ++reg)
                ls_lds[nl][reg][l16] = accl[mt][reg];
        }
    }
    __syncthreads();

    // --- epilogue: softmax over {self} U {4 rels}, per (node, col) ---
    #pragma unroll
    for (int nt = 0; nt < 4; ++nt) {
        int col = wc * 64 + nt * 16 + l16;
        float bl = bias_lang[col];
        int hh = wc * 4 + nt;                    // head of this col-tile
        #pragma unroll
        for (int mt = 0; mt < 2; ++mt) {
            int nl = wr_ * 8 + mt * 4 + quad;
            int node = node0 + nl;
            float Sv = svp[mt][nt];
            float ts = tsv[mt][nt];
            float td = tdv[mt][nt];
            float g0 = ls_lds[nl][0][hh] + td;
            float g1 = ls_lds[nl][1][hh] + td;
            float g2 = ls_lds[nl][2][hh] + td;
            float g3 = ls_lds[nl][3][hh] + td;
            float aS = ts + td;
            float lS = fmaxf(aS, 0.2f * aS);
            float l0 = fmaxf(g0, 0.2f * g0);
            float l1 = fmaxf(g1, 0.2f * g1);
            float l2 = fmaxf(g2, 0.2f * g2);
            float l3 = fmaxf(g3, 0.2f * g3);
            unsigned fl = flw[mt];
            bool v0 = (fl & 0x000000FFu) != 0, v1 = (fl & 0x0000FF00u) != 0;
            bool v2 = (fl & 0x00FF0000u) != 0, v3 = (fl & 0xFF000000u) != 0;
            float m = lS;
            if (v0) m = fmaxf(m, l0);
            if (v1) m = fmaxf(m, l1);
            if (v2) m = fmaxf(m, l2);
            if (v3) m = fmaxf(m, l3);
            float eS = __builtin_amdgcn_exp2f(lS - m);
            float e0 = v0 ? __builtin_amdgcn_exp2f(l0 - m) : 0.f;
            float e1 = v1 ? __builtin_amdgcn_exp2f(l1 - m) : 0.f;
            float e2 = v2 ? __builtin_amdgcn_exp2f(l2 - m) : 0.f;
            float e3 = v3 ? __builtin_amdgcn_exp2f(l3 - m) : 0.f;
            float sum = eS + e0 + e1 + e2 + e3;
            float o = eS * Sv + e0 * acc[mt][nt][0] + e1 * acc[mt][nt][1] +
                      e2 * acc[mt][nt][2] + e3 * acc[mt][nt][3];
            o = o / sum + bl;
            __builtin_nontemporal_store(o, &out[(unsigned)node * 128u + (unsigned)col]);
        }
    }
}

// ---------------------------------------------------------------------------
extern "C" void kernel_launch(void* const* d_in, const int* in_sizes, int n_in,
                              void* d_out, int out_size, void* d_ws, size_t ws_size,
                              hipStream_t stream) {
    const float* node_inp     = (const float*)d_in[0];
    const int*   edge_index   = (const int*)d_in[1];
    const int*   edge_type    = (const int*)d_in[2];
    const float* W_rel        = (const float*)d_in[3];
    const float* att_src_rel  = (const float*)d_in[4];
    const float* att_dst_rel  = (const float*)d_in[5];
    const float* bias_rel     = (const float*)d_in[6];
    const float* W_self       = (const float*)d_in[7];
    const float* W_cross      = (const float*)d_in[8];
    const float* att_src_lang = (const float*)d_in[9];
    const float* att_dst_lang = (const float*)d_in[10];
    const float* bias_lang    = (const float*)d_in[11];
    (void)in_sizes; (void)n_in;

    // workspace layout (bytes) — total 120,433,472
    const size_t SZ_XB   = (size_t)NREL * NN * 128 * 2;   // 51,200,000 (bf16)
    const size_t SZ_ES   = (size_t)NREL * NN * 8 * 2;     //  3,200,000 (bf16)
    const size_t SZ_TSD  = (size_t)NN * 16 * 2;           //  1,600,000 (bf16)
    const size_t SZ_GB4  = (size_t)NREL * NN * 128 * 2;   // 51,200,000 (bf16, node-major)
    const size_t SZ_WT   = 768 * 128 * 2;                 //    196,608
    const size_t SZ_WCT  = 144 * 128 * 2;                 //     36,864 (ext: +ls rows)
    const size_t SZ_BKT  = (size_t)NSEG * BCAP * 2;       //  8,800,000 (uint16 buckets)
    const size_t SZ_CNT  = (size_t)NSEG * 4;              //    800,000
    const size_t SZ_FLG  = (size_t)NN * 4;                //    200,000
    const size_t TOTAL = SZ_XB + 2 * SZ_ES + SZ_TSD + SZ_GB4 + SZ_WT + SZ_WCT +
                         SZ_BKT + SZ_CNT + SZ_FLG;

    if (ws_size < TOTAL) {
        fill_kernel<<<(out_size + 255) / 256, 256, 0, stream>>>((float*)d_out, out_size);
        return;
    }

    char* ws = (char*)d_ws;
    size_t o = 0;
    bf16*  Xb      = (bf16*)(ws + o);  o += SZ_XB;
    unsigned short* es_u = (unsigned short*)(ws + o); o += SZ_ES;
    unsigned short* ed_u = (unsigned short*)(ws + o); o += SZ_ES;
    unsigned short* tsd  = (unsigned short*)(ws + o); o += SZ_TSD;
    bf16*  Gb4     = (bf16*)(ws + o);  o += SZ_GB4;
    bf16*  Wt      = (bf16*)(ws + o);  o += SZ_WT;
    bf16*  Wct     = (bf16*)(ws + o);  o += SZ_WCT;
    unsigned short* bkt = (unsigned short*)(ws + o); o += SZ_BKT;
    int*   counts  = (int*)(ws + o);   o += SZ_CNT;
    unsigned char* flag = (unsigned char*)(ws + o);
    float* S       = (float*)d_out;  // S scratch in d_out; gemm_lang overwrites
    // Ab (bf16 node_inp, 12.8 MB) ALIASES Gb4: Ab is consumed by gemm_node,
    // Gb4 is first written by agg_kernel (strictly after) -> no overlap in time.
    bf16*  Ab      = Gb4;

    // zero bucket counters (graph-capturable memset node)
    hipMemsetAsync(counts, 0, SZ_CNT, stream);

    // fused prep (weights + Ab convert) + 1-edge-per-thread bucket scatter
    prep_scatter<<<(NE + 255) / 256, 256, 0, stream>>>(
        W_rel, W_self, W_cross, att_src_rel, att_dst_rel, att_src_lang,
        att_dst_lang, node_inp, edge_index, edge_type, Wt, Wct, Ab, counts, bkt);

    // 3x 256-wide GEMM planes (R10-measured staging, barrier-free epilogue)
    dim3 g1((NN + 63) / 64, 3);
    gemm_node<<<g1, 256, 0, stream>>>(Ab, Wt, Xb, S, es_u, ed_u, tsd, NN);

    // batched aggregation: 4 segments per wave, 16 lanes x 8 cols each
    dim3 ga(NN / 16, NREL);
    agg_kernel<<<ga, 256, 0, stream>>>(bkt, counts, Xb, es_u, ed_u, bias_rel, Gb4, flag);

    // fused cross-GEMM (+ls cols) + lang softmax -> d_out
    dim3 g2((NREL * NN + 63) / 64, 1);
    gemm_lang<<<g2, 256, 0, stream>>>(Gb4, Wct, flag, tsd, bias_lang, (float*)d_out);
}